// Round 3
// baseline (415.073 us; speedup 1.0000x reference)
//
#include <hip/hip_runtime.h>
#include <hip/hip_bf16.h>
#include <cstdint>

#define NPTS (2048 * 192)          // 393216 points
#define TBL  (1u << 19)            // hash table size per level
#define TMASK (TBL - 1u)
#define PBLOCKS (NPTS / 256)       // 1536

// geomspace(16, 2048, 16).astype(int)
__constant__ float LVLS[16] = {16.f, 22.f, 30.f, 42.f, 58.f, 80.f, 111.f, 153.f,
                               212.f, 294.f, 406.f, 561.f, 776.f, 1072.f, 1482.f, 2048.f};

#if __has_builtin(__builtin_amdgcn_sinf)
#define SIN_REV(x) __builtin_amdgcn_sinf(x)   // sin(2*pi*x)
#define COS_REV(x) __builtin_amdgcn_cosf(x)
#else
#define SIN_REV(x) __sinf(6.28318530717958647f * (x))
#define COS_REV(x) __cosf(6.28318530717958647f * (x))
#endif

// ---------------------------------------------------------------------------
// Fused NGP forward: hash-grid encode + density MLP + dir-PE + color MLP.
// One thread per point, no LDS, no __syncthreads. Rationale (round-2 PMC):
// encode saturates the TA/L2 gather pipe with VALU 7% idle; MLP saturates
// VALU/scalar-mem with TA idle. Fused, skewed waves on a CU overlap the two
// pipes instead of running them back-to-back as separate serialized kernels.
// Weights stay on the scalar path (wave-uniform s_load via K$).
// ---------------------------------------------------------------------------
__global__ __launch_bounds__(256) void k_fused(const float* __restrict__ x,
                                               const float* __restrict__ rdir,
                                               const float* __restrict__ tables,
                                               const float* __restrict__ dW1,
                                               const float* __restrict__ db1,
                                               const float* __restrict__ dW2,
                                               const float* __restrict__ db2,
                                               const float* __restrict__ cW1,
                                               const float* __restrict__ cb1,
                                               const float* __restrict__ cW2,
                                               const float* __restrict__ cb2,
                                               const float* __restrict__ cW3,
                                               const float* __restrict__ cb3,
                                               float* __restrict__ out)
{
    int p = blockIdx.x * 256 + threadIdx.x;
    size_t p3 = (size_t)p * 3;

    float xfx = x[p3 + 0] + 0.5f;
    float xfy = x[p3 + 1] + 0.5f;
    float xfz = x[p3 + 2] + 0.5f;

    // ---- hash-grid encode: 16 levels x 8 corners, trilinear ----
    float f[32];
#pragma unroll 4
    for (int lvl = 0; lvl < 16; ++lvl) {
        float s  = LVLS[lvl];
        float px = xfx * s, py = xfy * s, pz = xfz * s;
        float flx = floorf(px), fly = floorf(py), flz = floorf(pz);
        float frx = px - flx,   fry = py - fly,   frz = pz - flz;
        int ix = (int)flx, iy = (int)fly, iz = (int)flz;

        const float2* tb = (const float2*)tables + (size_t)lvl * TBL;

        uint32_t h[8];
#pragma unroll
        for (int c = 0; c < 8; ++c) {
            uint32_t cx = (uint32_t)(ix + (c & 1));
            uint32_t cy = (uint32_t)(iy + ((c >> 1) & 1));
            uint32_t cz = (uint32_t)(iz + ((c >> 2) & 1));
            h[c] = (cx * 1u ^ cy * 2654435761u ^ cz * 805459861u) & TMASK;
        }
        float2 v[8];
#pragma unroll
        for (int c = 0; c < 8; ++c) v[c] = tb[h[c]];

        float f0 = 0.f, f1 = 0.f;
#pragma unroll
        for (int c = 0; c < 8; ++c) {
            float w = ((c & 1)        ? frx : 1.f - frx)
                    * (((c >> 1) & 1) ? fry : 1.f - fry)
                    * (((c >> 2) & 1) ? frz : 1.f - frz);
            f0 += w * v[c].x;
            f1 += w * v[c].y;
        }
        f[2 * lvl]     = f0;
        f[2 * lvl + 1] = f1;
    }

    // ---- density layer 1: (32 -> 64), relu
    float h1[64];
#pragma unroll
    for (int j = 0; j < 64; ++j) h1[j] = db1[j];
#pragma unroll
    for (int k = 0; k < 32; ++k) {
        float a = f[k];
#pragma unroll
        for (int j = 0; j < 64; ++j) h1[j] = fmaf(a, dW1[k * 64 + j], h1[j]);
    }
#pragma unroll
    for (int j = 0; j < 64; ++j) h1[j] = fmaxf(h1[j], 0.f);

    // ---- density layer 2: (64 -> 16), linear
    float ls[16];
#pragma unroll
    for (int j = 0; j < 16; ++j) ls[j] = db2[j];
#pragma unroll
    for (int k = 0; k < 64; ++k) {
        float a = h1[k];
#pragma unroll
        for (int j = 0; j < 16; ++j) ls[j] = fmaf(a, dW2[k * 16 + j], ls[j]);
    }
    float ls0 = ls[0];

    // ---- color input vector: [log_sigma(16), rd(3), per-dim sin x4, cos x4]
    float av[43];
#pragma unroll
    for (int j = 0; j < 16; ++j) av[j] = ls[j];
    float rx = rdir[p3 + 0], ry = rdir[p3 + 1], rz = rdir[p3 + 2];
    av[16] = rx; av[17] = ry; av[18] = rz;
#pragma unroll
    for (int d = 0; d < 3; ++d) {
        float r = (d == 0) ? rx : ((d == 1) ? ry : rz);
#pragma unroll
        for (int l = 0; l < 4; ++l) {
            float rev = r * (float)(1 << l);      // exact pow2 scale
            av[19 + 8 * d + l]     = SIN_REV(rev);
            av[19 + 8 * d + 4 + l] = COS_REV(rev);
        }
    }

    // ---- color layer 1: (43 -> 64), relu
    float c1[64];
#pragma unroll
    for (int j = 0; j < 64; ++j) c1[j] = cb1[j];
#pragma unroll
    for (int k = 0; k < 43; ++k) {
        float a = av[k];
#pragma unroll
        for (int j = 0; j < 64; ++j) c1[j] = fmaf(a, cW1[k * 64 + j], c1[j]);
    }

    // ---- color layer 2: (64 -> 64), relu folded on input
    float c2[64];
#pragma unroll
    for (int j = 0; j < 64; ++j) c2[j] = cb2[j];
#pragma unroll
    for (int k = 0; k < 64; ++k) {
        float a = fmaxf(c1[k], 0.f);
#pragma unroll
        for (int j = 0; j < 64; ++j) c2[j] = fmaf(a, cW2[k * 64 + j], c2[j]);
    }

    // ---- color layer 3: (64 -> 3), sigmoid
    float col0 = cb3[0], col1 = cb3[1], col2 = cb3[2];
#pragma unroll
    for (int k = 0; k < 64; ++k) {
        float a = fmaxf(c2[k], 0.f);
        col0 = fmaf(a, cW3[k * 3 + 0], col0);
        col1 = fmaf(a, cW3[k * 3 + 1], col1);
        col2 = fmaf(a, cW3[k * 3 + 2], col2);
    }

    // ---- mask + outputs
    bool m = (xfx > 0.f) && (xfx < 1.f) && (xfy > 0.f) && (xfy < 1.f) &&
             (xfz > 0.f) && (xfz < 1.f);

    float s0 = m ? 1.f / (1.f + __expf(-col0)) : 0.f;
    float s1 = m ? 1.f / (1.f + __expf(-col1)) : 0.f;
    float s2 = m ? 1.f / (1.f + __expf(-col2)) : 0.f;
    float sg = m ? __expf(ls0) : 0.f;

    out[p3 + 0] = s0;
    out[p3 + 1] = s1;
    out[p3 + 2] = s2;
    out[(size_t)3 * NPTS + p] = sg;
}

extern "C" void kernel_launch(void* const* d_in, const int* in_sizes, int n_in,
                              void* d_out, int out_size, void* d_ws, size_t ws_size,
                              hipStream_t stream) {
    const float* x      = (const float*)d_in[0];
    const float* rdir   = (const float*)d_in[1];
    const float* tables = (const float*)d_in[2];
    const float* dW1 = (const float*)d_in[3];
    const float* db1 = (const float*)d_in[4];
    const float* dW2 = (const float*)d_in[5];
    const float* db2 = (const float*)d_in[6];
    const float* cW1 = (const float*)d_in[7];
    const float* cb1 = (const float*)d_in[8];
    const float* cW2 = (const float*)d_in[9];
    const float* cb2 = (const float*)d_in[10];
    const float* cW3 = (const float*)d_in[11];
    const float* cb3 = (const float*)d_in[12];
    float* out = (float*)d_out;

    k_fused<<<PBLOCKS, 256, 0, stream>>>(x, rdir, tables, dW1, db1, dW2, db2,
                                         cW1, cb1, cW2, cb2, cW3, cb3, out);
}

// Round 4
// 325.792 us; speedup vs baseline: 1.2740x; 1.2740x over previous
//
#include <hip/hip_runtime.h>
#include <hip/hip_bf16.h>
#include <cstdint>

#define NPTS (2048 * 192)          // 393216 points
#define TBL  (1u << 19)            // hash table size per level
#define TMASK (TBL - 1u)
#define PBLOCKS (NPTS / 256)       // 1536

// k_mlp geometry: 16-point groups, 4 waves/block, 8 groups/wave
#define MLP_BLOCKS 768             // 768*4 waves * 8 groups * 16 pts = 393216

// geomspace(16, 2048, 16).astype(int)
__constant__ float LVLS[16] = {16.f, 22.f, 30.f, 42.f, 58.f, 80.f, 111.f, 153.f,
                               212.f, 294.f, 406.f, 561.f, 776.f, 1072.f, 1482.f, 2048.f};

__device__ __forceinline__ uint32_t f2bf(float f) {
    uint32_t u = __float_as_uint(f);
    return (u + 0x7FFFu + ((u >> 16) & 1u)) >> 16;   // RNE bf16
}
__device__ __forceinline__ uint32_t pack2(float a, float b) {
    return f2bf(a) | (f2bf(b) << 16);
}

#if __has_builtin(__builtin_amdgcn_sinf)
#define SIN_REV(x) __builtin_amdgcn_sinf(x)   // sin(2*pi*x)
#define COS_REV(x) __builtin_amdgcn_cosf(x)
#else
#define SIN_REV(x) __sinf(6.28318530717958647f * (x))
#define COS_REV(x) __cosf(6.28318530717958647f * (x))
#endif

typedef __attribute__((ext_vector_type(8))) short bf16x8;   // MFMA A/B frag (4 VGPRs)
typedef __attribute__((ext_vector_type(4))) float f32x4;    // MFMA C/D frag

#define MFMA_BF16 __builtin_amdgcn_mfma_f32_16x16x32_bf16

// ---------------------------------------------------------------------------
// Kernel 1: hash-grid encode (unchanged from round 2 — known 156 us, bound by
// divergent gather request rate; lvl-major grid keeps L2 working set ~1 table).
// Output: feats[lvl][p] packed (bf16 f0 | bf16 f1 << 16) -> directly usable as
// MFMA B-fragment dwords in k_mlp.
// ---------------------------------------------------------------------------
__global__ __launch_bounds__(256) void k_encode(const float* __restrict__ x,
                                                const float* __restrict__ tables,
                                                uint32_t* __restrict__ feats)
{
    int lvl = blockIdx.x / PBLOCKS;
    int p   = (blockIdx.x - lvl * PBLOCKS) * 256 + threadIdx.x;

    size_t p3 = (size_t)p * 3;
    float s  = LVLS[lvl];
    float px = (x[p3 + 0] + 0.5f) * s;
    float py = (x[p3 + 1] + 0.5f) * s;
    float pz = (x[p3 + 2] + 0.5f) * s;

    float flx = floorf(px), fly = floorf(py), flz = floorf(pz);
    float frx = px - flx,   fry = py - fly,   frz = pz - flz;
    int ix = (int)flx, iy = (int)fly, iz = (int)flz;

    const float2* tb = (const float2*)tables + (size_t)lvl * TBL;

    uint32_t h[8];
#pragma unroll
    for (int c = 0; c < 8; ++c) {
        uint32_t cx = (uint32_t)(ix + (c & 1));
        uint32_t cy = (uint32_t)(iy + ((c >> 1) & 1));
        uint32_t cz = (uint32_t)(iz + ((c >> 2) & 1));
        h[c] = (cx * 1u ^ cy * 2654435761u ^ cz * 805459861u) & TMASK;
    }
    float2 v[8];
#pragma unroll
    for (int c = 0; c < 8; ++c) v[c] = tb[h[c]];

    float f0 = 0.f, f1 = 0.f;
#pragma unroll
    for (int c = 0; c < 8; ++c) {
        float w = ((c & 1)        ? frx : 1.f - frx)
                * (((c >> 1) & 1) ? fry : 1.f - fry)
                * (((c >> 2) & 1) ? frz : 1.f - frz);
        f0 += w * v[c].x;
        f1 += w * v[c].y;
    }
    feats[(size_t)lvl * NPTS + p] = pack2(f0, f1);
}

// ---------------------------------------------------------------------------
// MFMA helpers. Verified gfx950 layouts (guide §3):
//   A-frag:  A[m][k], m = lane&15, k = (lane>>4)*8 + j   (j = element 0..7)
//   B-frag:  B[k][n], n = lane&15, k = (lane>>4)*8 + j
//   C/D:     D[row][col], col = lane&15, row = (lane>>4)*4 + reg
// ---------------------------------------------------------------------------

// Load a weight A-fragment. W is [K][OUT] row-major (reference layout),
// A[m][k] = W[k][m]. k >= Kact -> 0, except k == Kact with biasfold != null
// -> biasfold[m] (constant-1-row bias folding). m >= Mact -> 0.
__device__ __forceinline__ bf16x8 load_wfrag(const float* __restrict__ W, int OUT,
                                             int Kact, int Mact, int k0, int m0,
                                             const float* __restrict__ biasfold,
                                             int lane)
{
    int m  = m0 + (lane & 15);
    int kq = k0 + ((lane >> 4) << 3);
    union { bf16x8 v; uint32_t d[4]; } u;
#pragma unroll
    for (int j = 0; j < 4; ++j) {
        float a0 = 0.f, a1 = 0.f;
        int ka = kq + 2 * j, kb = ka + 1;
        if (m < Mact) {
            a0 = (ka < Kact) ? W[(size_t)ka * OUT + m]
                             : ((biasfold && ka == Kact) ? biasfold[m] : 0.f);
            a1 = (kb < Kact) ? W[(size_t)kb * OUT + m]
                             : ((biasfold && kb == Kact) ? biasfold[m] : 0.f);
        }
        u.d[j] = f2bf(a0) | (f2bf(a1) << 16);
    }
    return u.v;
}

// Transition a 64-row activation (held as 4 D-tiles, pre-packed to bf16 pairs
// p01/p23 per tile) into one B-fragment k-tile. Tile pair (a,b) = tiles
// (2t, 2t+1). Derivation: target element e -> global row 32t+8q+e ->
// tile 2t+(q>>1), src quad 2(q&1)+(e>>2), src reg-pair (e>>1)&1.
__device__ __forceinline__ bf16x8 trans_frag(uint32_t p01a, uint32_t p23a,
                                             uint32_t p01b, uint32_t p23b, int lane)
{
    int q = lane >> 4, col = lane & 15;
    int srcA = (((q & 1) << 1) << 4) | col;   // src quad 2*(q&1)
    int srcB = srcA + 16;                     // src quad 2*(q&1)+1
    uint32_t a0 = (uint32_t)__shfl((int)p01a, srcA, 64);
    uint32_t b0 = (uint32_t)__shfl((int)p01b, srcA, 64);
    uint32_t a1 = (uint32_t)__shfl((int)p23a, srcA, 64);
    uint32_t b1 = (uint32_t)__shfl((int)p23b, srcA, 64);
    uint32_t a2 = (uint32_t)__shfl((int)p01a, srcB, 64);
    uint32_t b2 = (uint32_t)__shfl((int)p01b, srcB, 64);
    uint32_t a3 = (uint32_t)__shfl((int)p23a, srcB, 64);
    uint32_t b3 = (uint32_t)__shfl((int)p23b, srcB, 64);
    bool hi = q >= 2;
    union { bf16x8 v; uint32_t d[4]; } u;
    u.d[0] = hi ? b0 : a0;
    u.d[1] = hi ? b1 : a1;
    u.d[2] = hi ? b2 : a2;
    u.d[3] = hi ? b3 : a3;
    return u.v;
}

// av-vector row value for rows 16..63 (dir + positional encoding + pad).
// rows 16..18: rdir; 19+8d+l: sin(rd_d * 2^l rev); 19+8d+4+l: cos;
// row 43: 1.0 (cb1 bias fold); rows 44..63: 0.
__device__ __forceinline__ float pe_val(int r, float rx, float ry, float rz)
{
    int t = r - 19;
    int d = t >> 3;
    int s = t & 7;
    float comp = (d == 0) ? rx : ((d == 1) ? ry : rz);
    float a  = ldexpf(comp, s & 3);          // exact 2^l scale, in revolutions
    float sv = SIN_REV(a);
    float cv = COS_REV(a);
    float v  = (s < 4) ? sv : cv;
    if (r == 16) v = rx;
    if (r == 17) v = ry;
    if (r == 18) v = rz;
    if (r == 43) v = 1.0f;
    if (r > 43)  v = 0.0f;
    return v;
}

// ---------------------------------------------------------------------------
// Kernel 2: MLP stack on matrix cores. One wave = 16 points per group (N dim),
// 8 groups per wave. Weights resident as bf16 A-fragments (24 frags, 96 VGPR),
// activations chained D-layout -> B-layout via register shuffles. 24 MFMAs
// per group. Round-2 counters: VALU path took 157us at 46% busy with matrix
// pipe idle; this moves the 7.95 GFLOP onto MFMA.
// ---------------------------------------------------------------------------
__global__ __launch_bounds__(256) void k_mlp(const uint32_t* __restrict__ feats,
                                             const float* __restrict__ x,
                                             const float* __restrict__ rdir,
                                             const float* __restrict__ dW1,
                                             const float* __restrict__ db1,
                                             const float* __restrict__ dW2,
                                             const float* __restrict__ db2,
                                             const float* __restrict__ cW1,
                                             const float* __restrict__ cb1,
                                             const float* __restrict__ cW2,
                                             const float* __restrict__ cb2,
                                             const float* __restrict__ cW3,
                                             const float* __restrict__ cb3,
                                             float* __restrict__ out)
{
    int lane = threadIdx.x & 63;
    int q = lane >> 4, col = lane & 15;
    int wgid = blockIdx.x * 4 + (threadIdx.x >> 6);

    // ---- persistent weight fragments (loaded once per wave) ----
    bf16x8 A1[4], A2[2], A3[4][2], A4[4][2], A5[2];
#pragma unroll
    for (int mt = 0; mt < 4; ++mt)
        A1[mt] = load_wfrag(dW1, 64, 32, 64, 0, mt * 16, nullptr, lane);
#pragma unroll
    for (int kt = 0; kt < 2; ++kt)
        A2[kt] = load_wfrag(dW2, 16, 64, 16, kt * 32, 0, nullptr, lane);
#pragma unroll
    for (int mt = 0; mt < 4; ++mt)
#pragma unroll
        for (int kt = 0; kt < 2; ++kt) {
            A3[mt][kt] = load_wfrag(cW1, 64, 43, 64, kt * 32, mt * 16, cb1, lane);
            A4[mt][kt] = load_wfrag(cW2, 64, 64, 64, kt * 32, mt * 16, nullptr, lane);
        }
#pragma unroll
    for (int kt = 0; kt < 2; ++kt)
        A5[kt] = load_wfrag(cW3, 3, 64, 3, kt * 32, 0, nullptr, lane);

    for (int it = 0; it < 8; ++it) {
        int g = (wgid * 8 + it) << 4;        // point base of this 16-group
        int pt = g + col;
        size_t pt3 = (size_t)pt * 3;

        // ---- B-frag of feats: pair index = k/2 = q*4+w, packed bf16 in ws
        union { bf16x8 v; uint32_t d[4]; } Bf;
#pragma unroll
        for (int w = 0; w < 4; ++w)
            Bf.d[w] = feats[(size_t)(q * 4 + w) * NPTS + g + col];

        // ---- L1: feats(32) -> h1(64), bias, relu
        f32x4 T[4];
#pragma unroll
        for (int mt = 0; mt < 4; ++mt) {
            const float4 bb = *(const float4*)&db1[mt * 16 + q * 4];
            f32x4 c; c[0] = bb.x; c[1] = bb.y; c[2] = bb.z; c[3] = bb.w;
            T[mt] = MFMA_BF16(A1[mt], Bf.v, c, 0, 0, 0);
        }
        uint32_t p01[4], p23[4];
#pragma unroll
        for (int mt = 0; mt < 4; ++mt) {
            p01[mt] = pack2(fmaxf(T[mt][0], 0.f), fmaxf(T[mt][1], 0.f));
            p23[mt] = pack2(fmaxf(T[mt][2], 0.f), fmaxf(T[mt][3], 0.f));
        }
        bf16x8 Bh0 = trans_frag(p01[0], p23[0], p01[1], p23[1], lane);
        bf16x8 Bh1 = trans_frag(p01[2], p23[2], p01[3], p23[3], lane);

        // ---- L2: h1(64) -> log_sigma(16), bias, linear
        f32x4 Dls;
        {
            const float4 bb = *(const float4*)&db2[q * 4];
            f32x4 c; c[0] = bb.x; c[1] = bb.y; c[2] = bb.z; c[3] = bb.w;
            Dls = MFMA_BF16(A2[0], Bh0, c, 0, 0, 0);
            Dls = MFMA_BF16(A2[1], Bh1, Dls, 0, 0, 0);
        }
        uint32_t lp01 = pack2(Dls[0], Dls[1]);   // no relu on log_sigma
        uint32_t lp23 = pack2(Dls[2], Dls[3]);

        // ---- av B-frags: rows 0..15 = ls, 16..42 = dir PE, 43 = 1, rest 0
        float rx = rdir[pt3 + 0], ry = rdir[pt3 + 1], rz = rdir[pt3 + 2];

        union { bf16x8 v; uint32_t d[4]; } Ba0, Ba1;
        Ba0.v = trans_frag(lp01, lp23, lp01, lp23, lane);  // valid for q<2
        {
            int base = q << 3;                              // rows 8q+e
#pragma unroll
            for (int j = 0; j < 4; ++j) {
                uint32_t pk = pack2(pe_val(base + 2 * j, rx, ry, rz),
                                    pe_val(base + 2 * j + 1, rx, ry, rz));
                if (q >= 2) Ba0.d[j] = pk;                  // rows 16..31
            }
        }
        {
            int base = 32 + (q << 3);                       // rows 32..63
#pragma unroll
            for (int j = 0; j < 4; ++j)
                Ba1.d[j] = pack2(pe_val(base + 2 * j, rx, ry, rz),
                                 pe_val(base + 2 * j + 1, rx, ry, rz));
        }

        // ---- L3: av(43+1) -> c1(64), bias folded via row 43, relu
        f32x4 C1[4];
#pragma unroll
        for (int mt = 0; mt < 4; ++mt) {
            f32x4 c = {0.f, 0.f, 0.f, 0.f};
            c = MFMA_BF16(A3[mt][0], Ba0.v, c, 0, 0, 0);
            C1[mt] = MFMA_BF16(A3[mt][1], Ba1.v, c, 0, 0, 0);
        }
#pragma unroll
        for (int mt = 0; mt < 4; ++mt) {
            p01[mt] = pack2(fmaxf(C1[mt][0], 0.f), fmaxf(C1[mt][1], 0.f));
            p23[mt] = pack2(fmaxf(C1[mt][2], 0.f), fmaxf(C1[mt][3], 0.f));
        }
        bf16x8 Bc0 = trans_frag(p01[0], p23[0], p01[1], p23[1], lane);
        bf16x8 Bc1 = trans_frag(p01[2], p23[2], p01[3], p23[3], lane);

        // ---- L4: c1(64) -> c2(64), bias, relu
        f32x4 C2[4];
#pragma unroll
        for (int mt = 0; mt < 4; ++mt) {
            const float4 bb = *(const float4*)&cb2[mt * 16 + q * 4];
            f32x4 c; c[0] = bb.x; c[1] = bb.y; c[2] = bb.z; c[3] = bb.w;
            c = MFMA_BF16(A4[mt][0], Bc0, c, 0, 0, 0);
            C2[mt] = MFMA_BF16(A4[mt][1], Bc1, c, 0, 0, 0);
        }
#pragma unroll
        for (int mt = 0; mt < 4; ++mt) {
            p01[mt] = pack2(fmaxf(C2[mt][0], 0.f), fmaxf(C2[mt][1], 0.f));
            p23[mt] = pack2(fmaxf(C2[mt][2], 0.f), fmaxf(C2[mt][3], 0.f));
        }
        bf16x8 Bd0 = trans_frag(p01[0], p23[0], p01[1], p23[1], lane);
        bf16x8 Bd1 = trans_frag(p01[2], p23[2], p01[3], p23[3], lane);

        // ---- L5: c2(64) -> color(3), bias, sigmoid
        f32x4 c5 = {0.f, 0.f, 0.f, 0.f};
        if (q == 0) { c5[0] = cb3[0]; c5[1] = cb3[1]; c5[2] = cb3[2]; }
        f32x4 Dc = MFMA_BF16(A5[0], Bd0, c5, 0, 0, 0);
        Dc = MFMA_BF16(A5[1], Bd1, Dc, 0, 0, 0);

        // ---- outputs: rows 0..2 (colors) + ls row 0 (sigma) live in quad 0
        if (q == 0) {
            float xfx = x[pt3 + 0] + 0.5f;
            float xfy = x[pt3 + 1] + 0.5f;
            float xfz = x[pt3 + 2] + 0.5f;
            bool m = (xfx > 0.f) && (xfx < 1.f) && (xfy > 0.f) && (xfy < 1.f) &&
                     (xfz > 0.f) && (xfz < 1.f);
            out[pt3 + 0] = m ? 1.f / (1.f + __expf(-Dc[0])) : 0.f;
            out[pt3 + 1] = m ? 1.f / (1.f + __expf(-Dc[1])) : 0.f;
            out[pt3 + 2] = m ? 1.f / (1.f + __expf(-Dc[2])) : 0.f;
            out[(size_t)3 * NPTS + pt] = m ? __expf(Dls[0]) : 0.f;
        }
    }
}

extern "C" void kernel_launch(void* const* d_in, const int* in_sizes, int n_in,
                              void* d_out, int out_size, void* d_ws, size_t ws_size,
                              hipStream_t stream) {
    const float* x      = (const float*)d_in[0];
    const float* rdir   = (const float*)d_in[1];
    const float* tables = (const float*)d_in[2];
    const float* dW1 = (const float*)d_in[3];
    const float* db1 = (const float*)d_in[4];
    const float* dW2 = (const float*)d_in[5];
    const float* db2 = (const float*)d_in[6];
    const float* cW1 = (const float*)d_in[7];
    const float* cb1 = (const float*)d_in[8];
    const float* cW2 = (const float*)d_in[9];
    const float* cb2 = (const float*)d_in[10];
    const float* cW3 = (const float*)d_in[11];
    const float* cb3 = (const float*)d_in[12];
    float* out = (float*)d_out;

    uint32_t* feats = (uint32_t*)d_ws;   // 16 * NPTS * 4 B = 25.2 MB

    k_encode<<<PBLOCKS * 16, 256, 0, stream>>>(x, tables, feats);
    k_mlp<<<MLP_BLOCKS, 256, 0, stream>>>(feats, x, rdir, dW1, db1, dW2, db2,
                                          cW1, cb1, cW2, cb2, cW3, cb3, out);
}

// Round 5
// 267.706 us; speedup vs baseline: 1.5505x; 1.2170x over previous
//
#include <hip/hip_runtime.h>
#include <hip/hip_bf16.h>
#include <cstdint>

#define NPTS (2048 * 192)          // 393216 points
#define TBL  (1u << 19)            // hash table size per level
#define TMASK (TBL - 1u)
#define PBLOCKS (NPTS / 256)       // 1536
#define MLP_BLOCKS 768             // 768 blocks * 4 waves * 8 groups * 16 pts
#define P2 2654435761u
#define P3 805459861u

// geomspace(16, 2048, 16).astype(int)
__constant__ float LVLS[16] = {16.f, 22.f, 30.f, 42.f, 58.f, 80.f, 111.f, 153.f,
                               212.f, 294.f, 406.f, 561.f, 776.f, 1072.f, 1482.f, 2048.f};

__device__ __forceinline__ uint32_t f2bf(float f) {
    uint32_t u = __float_as_uint(f);
    return (u + 0x7FFFu + ((u >> 16) & 1u)) >> 16;   // RNE bf16
}
__device__ __forceinline__ uint32_t pack2(float a, float b) {
    return f2bf(a) | (f2bf(b) << 16);
}

#if __has_builtin(__builtin_amdgcn_sinf)
#define SIN_REV(x) __builtin_amdgcn_sinf(x)   // sin(2*pi*x)
#define COS_REV(x) __builtin_amdgcn_cosf(x)
#else
#define SIN_REV(x) __sinf(6.28318530717958647f * (x))
#define COS_REV(x) __cosf(6.28318530717958647f * (x))
#endif

typedef __attribute__((ext_vector_type(8))) short bf16x8;   // MFMA A/B frag
typedef __attribute__((ext_vector_type(4))) float f32x4;    // MFMA C/D frag

#define MFMA_BF16 __builtin_amdgcn_mfma_f32_16x16x32_bf16

// ---------------------------------------------------------------------------
// Kernel 0: pre-pack weight A-fragments (bf16, fragment layout) into d_ws.
// Round-4 PMC post-mortem: per-wave divergent weight loads in k_mlp cost
// ~38M L2 line-requests; prepacking turns the per-wave prologue into 24
// coalesced dwordx4 loads. Frag ids: A1[mt]=0..3, A2[kt]=4..5,
// A3[mt][kt]=6+2mt+kt, A4[mt][kt]=14+2mt+kt, A5[kt]=22..23.
// A-frag layout: A[m][k], m = lane&15, k = (lane>>4)*8 + j.
// ---------------------------------------------------------------------------
__global__ __launch_bounds__(256) void k_prep(const float* __restrict__ dW1,
                                              const float* __restrict__ dW2,
                                              const float* __restrict__ cW1,
                                              const float* __restrict__ cb1,
                                              const float* __restrict__ cW2,
                                              const float* __restrict__ cW3,
                                              uint4* __restrict__ wfrags)
{
    int t = blockIdx.x * 256 + threadIdx.x;
    if (t >= 24 * 64) return;
    int frag = t >> 6, lane = t & 63;

    const float* W; const float* bfold = nullptr;
    int OUT, Kact, Mact, k0, m0;
    if (frag < 4)       { W = dW1; OUT = 64; Kact = 32; Mact = 64; k0 = 0;               m0 = frag * 16; }
    else if (frag < 6)  { W = dW2; OUT = 16; Kact = 64; Mact = 16; k0 = (frag - 4) * 32; m0 = 0; }
    else if (frag < 14) { int i = frag - 6;  W = cW1; OUT = 64; Kact = 43; Mact = 64;
                          k0 = (i & 1) * 32; m0 = (i >> 1) * 16; bfold = cb1; }
    else if (frag < 22) { int i = frag - 14; W = cW2; OUT = 64; Kact = 64; Mact = 64;
                          k0 = (i & 1) * 32; m0 = (i >> 1) * 16; }
    else                { W = cW3; OUT = 3;  Kact = 64; Mact = 3;  k0 = (frag - 22) * 32; m0 = 0; }

    int m  = m0 + (lane & 15);
    int kq = k0 + ((lane >> 4) << 3);
    uint32_t d[4];
#pragma unroll
    for (int j = 0; j < 4; ++j) {
        float a0 = 0.f, a1 = 0.f;
        int ka = kq + 2 * j, kb = ka + 1;
        if (m < Mact) {
            a0 = (ka < Kact) ? W[(size_t)ka * OUT + m]
                             : ((bfold && ka == Kact) ? bfold[m] : 0.f);
            a1 = (kb < Kact) ? W[(size_t)kb * OUT + m]
                             : ((bfold && kb == Kact) ? bfold[m] : 0.f);
        }
        d[j] = f2bf(a0) | (f2bf(a1) << 16);
    }
    wfrags[t] = make_uint4(d[0], d[1], d[2], d[3]);
}

// ---------------------------------------------------------------------------
// Kernel 1: hash-grid encode. One thread per (point, level), lvl-major grid
// (keeps ~1 table in each XCD L2). Bound by L2 random-request rate, so this
// round cuts REQUEST COUNT: (a) masked points skip all gathers (25% of
// points); (b) x-corner pairs (ix even) hash to adjacent slots h, h^1 since
// PRIME_x == 1 -> one float4 load covers both corners (4 reqs vs 8).
// ---------------------------------------------------------------------------
__global__ __launch_bounds__(256) void k_encode(const float* __restrict__ x,
                                                const float* __restrict__ tables,
                                                uint32_t* __restrict__ feats)
{
    int lvl = blockIdx.x / PBLOCKS;
    int p   = (blockIdx.x - lvl * PBLOCKS) * 256 + threadIdx.x;

    size_t p3 = (size_t)p * 3;
    float x0 = x[p3 + 0] + 0.5f;
    float x1 = x[p3 + 1] + 0.5f;
    float x2 = x[p3 + 2] + 0.5f;
    size_t oidx = (size_t)lvl * NPTS + p;

    bool m = (x0 > 0.f) && (x0 < 1.f) && (x1 > 0.f) && (x1 < 1.f) &&
             (x2 > 0.f) && (x2 < 1.f);
    if (!m) { feats[oidx] = 0u; return; }   // masked: features never used

    float s  = LVLS[lvl];
    float px = x0 * s, py = x1 * s, pz = x2 * s;
    float flx = floorf(px), fly = floorf(py), flz = floorf(pz);
    float frx = px - flx,   fry = py - fly,   frz = pz - flz;
    int ix = (int)flx, iy = (int)fly, iz = (int)flz;
    uint32_t ux = (uint32_t)ix, uy = (uint32_t)iy, uz = (uint32_t)iz;

    // per-(cy,cz) hash bases; corner index c = xbit + 2*ybit + 4*zbit
    uint32_t base[4];
    base[0] = (uy * P2) ^ (uz * P3);
    base[1] = ((uy + 1u) * P2) ^ (uz * P3);
    base[2] = (uy * P2) ^ ((uz + 1u) * P3);
    base[3] = ((uy + 1u) * P2) ^ ((uz + 1u) * P3);

    const float2* tb = (const float2*)tables + (size_t)lvl * TBL;

    float2 v[8];
    if ((ix & 1) == 0) {
        // even ix: corners (ix, ix+1) live at (h, h^1) -> aligned 16-B pair
        const float4* tb4 = (const float4*)tb;
#pragma unroll
        for (int cc = 0; cc < 4; ++cc) {
            uint32_t h0 = (base[cc] ^ ux) & TMASK;
            float4 qv = tb4[h0 >> 1];
            bool hi = (h0 & 1u) != 0u;
            float2 e0 = hi ? make_float2(qv.z, qv.w) : make_float2(qv.x, qv.y);
            float2 e1 = hi ? make_float2(qv.x, qv.y) : make_float2(qv.z, qv.w);
            v[(cc << 1)]     = e0;   // x-corner 0
            v[(cc << 1) | 1] = e1;   // x-corner 1
        }
    } else {
        uint32_t h[8];
#pragma unroll
        for (int c = 0; c < 8; ++c)
            h[c] = (base[c >> 1] ^ (ux + (uint32_t)(c & 1))) & TMASK;
#pragma unroll
        for (int c = 0; c < 8; ++c) v[c] = tb[h[c]];
    }

    float f0 = 0.f, f1 = 0.f;
#pragma unroll
    for (int c = 0; c < 8; ++c) {
        float w = ((c & 1)        ? frx : 1.f - frx)
                * (((c >> 1) & 1) ? fry : 1.f - fry)
                * (((c >> 2) & 1) ? frz : 1.f - frz);
        f0 += w * v[c].x;
        f1 += w * v[c].y;
    }
    feats[oidx] = pack2(f0, f1);
}

// ---------------------------------------------------------------------------
// MFMA layout helpers (verified gfx950):
//   A-frag: A[m][k], m = lane&15, k = (lane>>4)*8 + j
//   B-frag: B[k][n], n = lane&15, k = (lane>>4)*8 + j
//   C/D:    D[row][col], col = lane&15, row = (lane>>4)*4 + reg
// ---------------------------------------------------------------------------
__device__ __forceinline__ bf16x8 trans_frag(uint32_t p01a, uint32_t p23a,
                                             uint32_t p01b, uint32_t p23b, int lane)
{
    int q = lane >> 4, col = lane & 15;
    int srcA = (((q & 1) << 1) << 4) | col;   // src quad 2*(q&1)
    int srcB = srcA + 16;                     // src quad 2*(q&1)+1
    uint32_t a0 = (uint32_t)__shfl((int)p01a, srcA, 64);
    uint32_t b0 = (uint32_t)__shfl((int)p01b, srcA, 64);
    uint32_t a1 = (uint32_t)__shfl((int)p23a, srcA, 64);
    uint32_t b1 = (uint32_t)__shfl((int)p23b, srcA, 64);
    uint32_t a2 = (uint32_t)__shfl((int)p01a, srcB, 64);
    uint32_t b2 = (uint32_t)__shfl((int)p01b, srcB, 64);
    uint32_t a3 = (uint32_t)__shfl((int)p23a, srcB, 64);
    uint32_t b3 = (uint32_t)__shfl((int)p23b, srcB, 64);
    bool hi = q >= 2;
    union { bf16x8 v; uint32_t d[4]; } u;
    u.d[0] = hi ? b0 : a0;
    u.d[1] = hi ? b1 : a1;
    u.d[2] = hi ? b2 : a2;
    u.d[3] = hi ? b3 : a3;
    return u.v;
}

// av-vector row value for rows 16..63 (dir + positional encoding + pad)
__device__ __forceinline__ float pe_val(int r, float rx, float ry, float rz)
{
    int t = r - 19;
    int d = t >> 3;
    int s = t & 7;
    float comp = (d == 0) ? rx : ((d == 1) ? ry : rz);
    float a  = ldexpf(comp, s & 3);          // exact 2^l scale, revolutions
    float sv = SIN_REV(a);
    float cv = COS_REV(a);
    float v  = (s < 4) ? sv : cv;
    if (r == 16) v = rx;
    if (r == 17) v = ry;
    if (r == 18) v = rz;
    if (r == 43) v = 1.0f;
    if (r > 43)  v = 0.0f;
    return v;
}

// ---------------------------------------------------------------------------
// Kernel 2: MLP stack on matrix cores. Wave = 16 points per group (N dim),
// 8 groups/wave. Weight fragments loaded coalesced from prepacked d_ws.
// ---------------------------------------------------------------------------
__global__ __launch_bounds__(256) void k_mlp(const uint32_t* __restrict__ feats,
                                             const uint4* __restrict__ wfrags,
                                             const float* __restrict__ x,
                                             const float* __restrict__ rdir,
                                             const float* __restrict__ db1,
                                             const float* __restrict__ db2,
                                             const float* __restrict__ cb2,
                                             const float* __restrict__ cb3,
                                             float* __restrict__ out)
{
    int lane = threadIdx.x & 63;
    int q = lane >> 4, col = lane & 15;
    int wgid = blockIdx.x * 4 + (threadIdx.x >> 6);

    // ---- persistent weight fragments: 24 coalesced dwordx4 loads ----
    union { bf16x8 v; uint4 u; } wf;
    bf16x8 A1[4], A2[2], A3[4][2], A4[4][2], A5[2];
#pragma unroll
    for (int mt = 0; mt < 4; ++mt) { wf.u = wfrags[(0 + mt) * 64 + lane]; A1[mt] = wf.v; }
#pragma unroll
    for (int kt = 0; kt < 2; ++kt) { wf.u = wfrags[(4 + kt) * 64 + lane]; A2[kt] = wf.v; }
#pragma unroll
    for (int mt = 0; mt < 4; ++mt)
#pragma unroll
        for (int kt = 0; kt < 2; ++kt) {
            wf.u = wfrags[(6 + 2 * mt + kt) * 64 + lane];  A3[mt][kt] = wf.v;
            wf.u = wfrags[(14 + 2 * mt + kt) * 64 + lane]; A4[mt][kt] = wf.v;
        }
#pragma unroll
    for (int kt = 0; kt < 2; ++kt) { wf.u = wfrags[(22 + kt) * 64 + lane]; A5[kt] = wf.v; }

    for (int it = 0; it < 8; ++it) {
        int g = (wgid * 8 + it) << 4;        // point base of this 16-group
        int pt = g + col;
        size_t pt3 = (size_t)pt * 3;

        // ---- B-frag of feats: pair index k/2 = q*4+w
        union { bf16x8 v; uint32_t d[4]; } Bf;
#pragma unroll
        for (int w = 0; w < 4; ++w)
            Bf.d[w] = feats[(size_t)(q * 4 + w) * NPTS + g + col];

        // ---- L1: feats(32) -> h1(64), bias, relu
        f32x4 T[4];
#pragma unroll
        for (int mt = 0; mt < 4; ++mt) {
            const float4 bb = *(const float4*)&db1[mt * 16 + q * 4];
            f32x4 c; c[0] = bb.x; c[1] = bb.y; c[2] = bb.z; c[3] = bb.w;
            T[mt] = MFMA_BF16(A1[mt], Bf.v, c, 0, 0, 0);
        }
        uint32_t p01[4], p23[4];
#pragma unroll
        for (int mt = 0; mt < 4; ++mt) {
            p01[mt] = pack2(fmaxf(T[mt][0], 0.f), fmaxf(T[mt][1], 0.f));
            p23[mt] = pack2(fmaxf(T[mt][2], 0.f), fmaxf(T[mt][3], 0.f));
        }
        bf16x8 Bh0 = trans_frag(p01[0], p23[0], p01[1], p23[1], lane);
        bf16x8 Bh1 = trans_frag(p01[2], p23[2], p01[3], p23[3], lane);

        // ---- L2: h1(64) -> log_sigma(16), bias, linear
        f32x4 Dls;
        {
            const float4 bb = *(const float4*)&db2[q * 4];
            f32x4 c; c[0] = bb.x; c[1] = bb.y; c[2] = bb.z; c[3] = bb.w;
            Dls = MFMA_BF16(A2[0], Bh0, c, 0, 0, 0);
            Dls = MFMA_BF16(A2[1], Bh1, Dls, 0, 0, 0);
        }
        uint32_t lp01 = pack2(Dls[0], Dls[1]);
        uint32_t lp23 = pack2(Dls[2], Dls[3]);

        // ---- av B-frags: rows 0..15 = ls, 16..42 = dir PE, 43 = 1, rest 0
        float rx = rdir[pt3 + 0], ry = rdir[pt3 + 1], rz = rdir[pt3 + 2];

        union { bf16x8 v; uint32_t d[4]; } Ba0, Ba1;
        Ba0.v = trans_frag(lp01, lp23, lp01, lp23, lane);  // valid for q<2
        {
            int base = q << 3;
#pragma unroll
            for (int j = 0; j < 4; ++j) {
                uint32_t pk = pack2(pe_val(base + 2 * j, rx, ry, rz),
                                    pe_val(base + 2 * j + 1, rx, ry, rz));
                if (q >= 2) Ba0.d[j] = pk;                  // rows 16..31
            }
        }
        {
            int base = 32 + (q << 3);
#pragma unroll
            for (int j = 0; j < 4; ++j)
                Ba1.d[j] = pack2(pe_val(base + 2 * j, rx, ry, rz),
                                 pe_val(base + 2 * j + 1, rx, ry, rz));
        }

        // ---- L3: av(43+1) -> c1(64), bias folded via row 43, relu
        f32x4 C1[4];
#pragma unroll
        for (int mt = 0; mt < 4; ++mt) {
            f32x4 c = {0.f, 0.f, 0.f, 0.f};
            c = MFMA_BF16(A3[mt][0], Ba0.v, c, 0, 0, 0);
            C1[mt] = MFMA_BF16(A3[mt][1], Ba1.v, c, 0, 0, 0);
        }
#pragma unroll
        for (int mt = 0; mt < 4; ++mt) {
            p01[mt] = pack2(fmaxf(C1[mt][0], 0.f), fmaxf(C1[mt][1], 0.f));
            p23[mt] = pack2(fmaxf(C1[mt][2], 0.f), fmaxf(C1[mt][3], 0.f));
        }
        bf16x8 Bc0 = trans_frag(p01[0], p23[0], p01[1], p23[1], lane);
        bf16x8 Bc1 = trans_frag(p01[2], p23[2], p01[3], p23[3], lane);

        // ---- L4: c1(64) -> c2(64), bias, relu
        f32x4 C2[4];
#pragma unroll
        for (int mt = 0; mt < 4; ++mt) {
            const float4 bb = *(const float4*)&cb2[mt * 16 + q * 4];
            f32x4 c; c[0] = bb.x; c[1] = bb.y; c[2] = bb.z; c[3] = bb.w;
            c = MFMA_BF16(A4[mt][0], Bc0, c, 0, 0, 0);
            C2[mt] = MFMA_BF16(A4[mt][1], Bc1, c, 0, 0, 0);
        }
#pragma unroll
        for (int mt = 0; mt < 4; ++mt) {
            p01[mt] = pack2(fmaxf(C2[mt][0], 0.f), fmaxf(C2[mt][1], 0.f));
            p23[mt] = pack2(fmaxf(C2[mt][2], 0.f), fmaxf(C2[mt][3], 0.f));
        }
        bf16x8 Bd0 = trans_frag(p01[0], p23[0], p01[1], p23[1], lane);
        bf16x8 Bd1 = trans_frag(p01[2], p23[2], p01[3], p23[3], lane);

        // ---- L5: c2(64) -> color(3), bias, sigmoid
        f32x4 c5 = {0.f, 0.f, 0.f, 0.f};
        if (q == 0) { c5[0] = cb3[0]; c5[1] = cb3[1]; c5[2] = cb3[2]; }
        f32x4 Dc = MFMA_BF16(A5[0], Bd0, c5, 0, 0, 0);
        Dc = MFMA_BF16(A5[1], Bd1, Dc, 0, 0, 0);

        // ---- outputs
        if (q == 0) {
            float xfx = x[pt3 + 0] + 0.5f;
            float xfy = x[pt3 + 1] + 0.5f;
            float xfz = x[pt3 + 2] + 0.5f;
            bool m = (xfx > 0.f) && (xfx < 1.f) && (xfy > 0.f) && (xfy < 1.f) &&
                     (xfz > 0.f) && (xfz < 1.f);
            out[pt3 + 0] = m ? 1.f / (1.f + __expf(-Dc[0])) : 0.f;
            out[pt3 + 1] = m ? 1.f / (1.f + __expf(-Dc[1])) : 0.f;
            out[pt3 + 2] = m ? 1.f / (1.f + __expf(-Dc[2])) : 0.f;
            out[(size_t)3 * NPTS + pt] = m ? __expf(Dls[0]) : 0.f;
        }
    }
}

extern "C" void kernel_launch(void* const* d_in, const int* in_sizes, int n_in,
                              void* d_out, int out_size, void* d_ws, size_t ws_size,
                              hipStream_t stream) {
    const float* x      = (const float*)d_in[0];
    const float* rdir   = (const float*)d_in[1];
    const float* tables = (const float*)d_in[2];
    const float* dW1 = (const float*)d_in[3];
    const float* db1 = (const float*)d_in[4];
    const float* dW2 = (const float*)d_in[5];
    const float* db2 = (const float*)d_in[6];
    const float* cW1 = (const float*)d_in[7];
    const float* cb1 = (const float*)d_in[8];
    const float* cW2 = (const float*)d_in[9];
    const float* cb2 = (const float*)d_in[10];
    const float* cW3 = (const float*)d_in[11];
    const float* cb3 = (const float*)d_in[12];
    float* out = (float*)d_out;

    uint4*    wfrags = (uint4*)d_ws;                        // 24 KB
    uint32_t* feats  = (uint32_t*)((char*)d_ws + 32768);    // 16*NPTS*4 B

    k_prep<<<6, 256, 0, stream>>>(dW1, dW2, cW1, cb1, cW2, cW3, wfrags);
    k_encode<<<PBLOCKS * 16, 256, 0, stream>>>(x, tables, feats);
    k_mlp<<<MLP_BLOCKS, 256, 0, stream>>>(feats, wfrags, x, rdir,
                                          db1, db2, cb2, cb3, out);
}

// Round 6
// 256.932 us; speedup vs baseline: 1.6155x; 1.0419x over previous
//
#include <hip/hip_runtime.h>
#include <hip/hip_bf16.h>
#include <cstdint>

#define NPTS (2048 * 192)          // 393216 points
#define TBL  (1u << 19)            // hash table size per level
#define TMASK (TBL - 1u)
#define PBLOCKS (NPTS / 256)       // 1536 blocks per level
#define ENC_BLOCKS (PBLOCKS * 16)  // 24576
#define PREP_BLOCKS 6              // 24 frags * 64 lanes / 256
#define MLP_BLOCKS 768             // 768 blocks * 4 waves * 8 groups * 16 pts
#define P2 2654435761u
#define P3 805459861u

// geomspace(16, 2048, 16).astype(int)
__constant__ float LVLS[16] = {16.f, 22.f, 30.f, 42.f, 58.f, 80.f, 111.f, 153.f,
                               212.f, 294.f, 406.f, 561.f, 776.f, 1072.f, 1482.f, 2048.f};

__device__ __forceinline__ uint32_t f2bf(float f) {
    uint32_t u = __float_as_uint(f);
    return (u + 0x7FFFu + ((u >> 16) & 1u)) >> 16;   // RNE bf16
}
__device__ __forceinline__ uint32_t pack2(float a, float b) {
    return f2bf(a) | (f2bf(b) << 16);
}

#if __has_builtin(__builtin_amdgcn_sinf)
#define SIN_REV(x) __builtin_amdgcn_sinf(x)   // sin(2*pi*x)
#define COS_REV(x) __builtin_amdgcn_cosf(x)
#else
#define SIN_REV(x) __sinf(6.28318530717958647f * (x))
#define COS_REV(x) __cosf(6.28318530717958647f * (x))
#endif

typedef __attribute__((ext_vector_type(8))) short bf16x8;   // MFMA A/B frag
typedef __attribute__((ext_vector_type(4))) float f32x4;    // MFMA C/D frag

#define MFMA_BF16 __builtin_amdgcn_mfma_f32_16x16x32_bf16

// ---------------------------------------------------------------------------
// Kernel 1: hash-grid encode + (tail blocks) weight-fragment prepack.
//
// Encode block mapping is XCD-affine: blocks of level L all have
// blockIdx%8 == L%8 (HW round-robins consecutive blockIdx across the 8
// XCDs), levels 0-7 in the first half of the dispatch, 8-15 in the second.
// Each XCD therefore streams ONE 4MB table at a time through its 4MB L2
// instead of all 16 interleaved (round-5 PMC: 277MB FETCH = tables pulled
// ~4x per XCD; this mapping targets ~1x).
//
// Request-count tricks kept from round 5: masked points skip gathers;
// even-ix corner pairs (h, h^1) fetched as one float4.
// ---------------------------------------------------------------------------
__global__ __launch_bounds__(256) void k_encode(const float* __restrict__ x,
                                                const float* __restrict__ tables,
                                                uint32_t* __restrict__ feats,
                                                const float* __restrict__ dW1,
                                                const float* __restrict__ dW2,
                                                const float* __restrict__ cW1,
                                                const float* __restrict__ cb1,
                                                const float* __restrict__ cW2,
                                                const float* __restrict__ cW3,
                                                uint4* __restrict__ wfrags)
{
    if (blockIdx.x >= ENC_BLOCKS) {
        // ---- weight prepack (6 tail blocks; k_mlp runs after this kernel) ----
        int t = (blockIdx.x - ENC_BLOCKS) * 256 + threadIdx.x;
        if (t >= 24 * 64) return;
        int frag = t >> 6, lane = t & 63;
        const float* W; const float* bfold = nullptr;
        int OUT, Kact, Mact, k0, m0;
        if (frag < 4)       { W = dW1; OUT = 64; Kact = 32; Mact = 64; k0 = 0;               m0 = frag * 16; }
        else if (frag < 6)  { W = dW2; OUT = 16; Kact = 64; Mact = 16; k0 = (frag - 4) * 32; m0 = 0; }
        else if (frag < 14) { int i = frag - 6;  W = cW1; OUT = 64; Kact = 43; Mact = 64;
                              k0 = (i & 1) * 32; m0 = (i >> 1) * 16; bfold = cb1; }
        else if (frag < 22) { int i = frag - 14; W = cW2; OUT = 64; Kact = 64; Mact = 64;
                              k0 = (i & 1) * 32; m0 = (i >> 1) * 16; }
        else                { W = cW3; OUT = 3;  Kact = 64; Mact = 3;  k0 = (frag - 22) * 32; m0 = 0; }
        int m  = m0 + (lane & 15);
        int kq = k0 + ((lane >> 4) << 3);
        uint32_t d[4];
#pragma unroll
        for (int j = 0; j < 4; ++j) {
            float a0 = 0.f, a1 = 0.f;
            int ka = kq + 2 * j, kb = ka + 1;
            if (m < Mact) {
                a0 = (ka < Kact) ? W[(size_t)ka * OUT + m]
                                 : ((bfold && ka == Kact) ? bfold[m] : 0.f);
                a1 = (kb < Kact) ? W[(size_t)kb * OUT + m]
                                 : ((bfold && kb == Kact) ? bfold[m] : 0.f);
            }
            d[j] = f2bf(a0) | (f2bf(a1) << 16);
        }
        wfrags[t] = make_uint4(d[0], d[1], d[2], d[3]);
        return;
    }

    // ---- XCD-affine decode of (level, point-block) ----
    int xs   = blockIdx.x & 7;          // XCD slot
    int i    = blockIdx.x >> 3;         // 0..3071
    int half = i / PBLOCKS;             // 0: levels 0-7, 1: levels 8-15
    int pb   = i - half * PBLOCKS;      // point-block 0..1535
    int lvl  = xs + (half << 3);
    int p    = pb * 256 + threadIdx.x;

    size_t p3 = (size_t)p * 3;
    float x0 = x[p3 + 0] + 0.5f;
    float x1 = x[p3 + 1] + 0.5f;
    float x2 = x[p3 + 2] + 0.5f;
    size_t oidx = (size_t)lvl * NPTS + p;

    bool m = (x0 > 0.f) && (x0 < 1.f) && (x1 > 0.f) && (x1 < 1.f) &&
             (x2 > 0.f) && (x2 < 1.f);
    if (!m) { feats[oidx] = 0u; return; }   // masked: features never used

    float s  = LVLS[lvl];
    float px = x0 * s, py = x1 * s, pz = x2 * s;
    float flx = floorf(px), fly = floorf(py), flz = floorf(pz);
    float frx = px - flx,   fry = py - fly,   frz = pz - flz;
    int ix = (int)flx, iy = (int)fly, iz = (int)flz;
    uint32_t ux = (uint32_t)ix, uy = (uint32_t)iy, uz = (uint32_t)iz;

    uint32_t base[4];
    base[0] = (uy * P2) ^ (uz * P3);
    base[1] = ((uy + 1u) * P2) ^ (uz * P3);
    base[2] = (uy * P2) ^ ((uz + 1u) * P3);
    base[3] = ((uy + 1u) * P2) ^ ((uz + 1u) * P3);

    const float2* tb = (const float2*)tables + (size_t)lvl * TBL;

    float2 v[8];
    if ((ix & 1) == 0) {
        const float4* tb4 = (const float4*)tb;
#pragma unroll
        for (int cc = 0; cc < 4; ++cc) {
            uint32_t h0 = (base[cc] ^ ux) & TMASK;
            float4 qv = tb4[h0 >> 1];
            bool hi = (h0 & 1u) != 0u;
            float2 e0 = hi ? make_float2(qv.z, qv.w) : make_float2(qv.x, qv.y);
            float2 e1 = hi ? make_float2(qv.x, qv.y) : make_float2(qv.z, qv.w);
            v[(cc << 1)]     = e0;
            v[(cc << 1) | 1] = e1;
        }
    } else {
        uint32_t h[8];
#pragma unroll
        for (int c = 0; c < 8; ++c)
            h[c] = (base[c >> 1] ^ (ux + (uint32_t)(c & 1))) & TMASK;
#pragma unroll
        for (int c = 0; c < 8; ++c) v[c] = tb[h[c]];
    }

    float f0 = 0.f, f1 = 0.f;
#pragma unroll
    for (int c = 0; c < 8; ++c) {
        float w = ((c & 1)        ? frx : 1.f - frx)
                * (((c >> 1) & 1) ? fry : 1.f - fry)
                * (((c >> 2) & 1) ? frz : 1.f - frz);
        f0 += w * v[c].x;
        f1 += w * v[c].y;
    }
    feats[oidx] = pack2(f0, f1);
}

// ---------------------------------------------------------------------------
// MFMA layout helpers (verified gfx950):
//   A-frag: A[m][k], m = lane&15, k = (lane>>4)*8 + j
//   B-frag: B[k][n], n = lane&15, k = (lane>>4)*8 + j
//   C/D:    D[row][col], col = lane&15, row = (lane>>4)*4 + reg
// ---------------------------------------------------------------------------
__device__ __forceinline__ bf16x8 trans_frag(uint32_t p01a, uint32_t p23a,
                                             uint32_t p01b, uint32_t p23b, int lane)
{
    int q = lane >> 4, col = lane & 15;
    int srcA = (((q & 1) << 1) << 4) | col;   // src quad 2*(q&1)
    int srcB = srcA + 16;                     // src quad 2*(q&1)+1
    uint32_t a0 = (uint32_t)__shfl((int)p01a, srcA, 64);
    uint32_t b0 = (uint32_t)__shfl((int)p01b, srcA, 64);
    uint32_t a1 = (uint32_t)__shfl((int)p23a, srcA, 64);
    uint32_t b1 = (uint32_t)__shfl((int)p23b, srcA, 64);
    uint32_t a2 = (uint32_t)__shfl((int)p01a, srcB, 64);
    uint32_t b2 = (uint32_t)__shfl((int)p01b, srcB, 64);
    uint32_t a3 = (uint32_t)__shfl((int)p23a, srcB, 64);
    uint32_t b3 = (uint32_t)__shfl((int)p23b, srcB, 64);
    bool hi = q >= 2;
    union { bf16x8 v; uint32_t d[4]; } u;
    u.d[0] = hi ? b0 : a0;
    u.d[1] = hi ? b1 : a1;
    u.d[2] = hi ? b2 : a2;
    u.d[3] = hi ? b3 : a3;
    return u.v;
}

// av-vector row value for rows 16..63 (dir + positional encoding + pad)
__device__ __forceinline__ float pe_val(int r, float rx, float ry, float rz)
{
    int t = r - 19;
    int d = t >> 3;
    int s = t & 7;
    float comp = (d == 0) ? rx : ((d == 1) ? ry : rz);
    float a  = ldexpf(comp, s & 3);          // exact 2^l scale, revolutions
    float sv = SIN_REV(a);
    float cv = COS_REV(a);
    float v  = (s < 4) ? sv : cv;
    if (r == 16) v = rx;
    if (r == 17) v = ry;
    if (r == 18) v = rz;
    if (r == 43) v = 1.0f;
    if (r > 43)  v = 0.0f;
    return v;
}

// ---------------------------------------------------------------------------
// Kernel 2: MLP stack on matrix cores. Wave = 16 points per group (N dim),
// 8 groups/wave. Weight fragments loaded coalesced from prepacked d_ws.
// ---------------------------------------------------------------------------
__global__ __launch_bounds__(256) void k_mlp(const uint32_t* __restrict__ feats,
                                             const uint4* __restrict__ wfrags,
                                             const float* __restrict__ x,
                                             const float* __restrict__ rdir,
                                             const float* __restrict__ db1,
                                             const float* __restrict__ db2,
                                             const float* __restrict__ cb2,
                                             const float* __restrict__ cb3,
                                             float* __restrict__ out)
{
    int lane = threadIdx.x & 63;
    int q = lane >> 4, col = lane & 15;
    int wgid = blockIdx.x * 4 + (threadIdx.x >> 6);

    // ---- persistent weight fragments: 24 coalesced dwordx4 loads ----
    union { bf16x8 v; uint4 u; } wf;
    bf16x8 A1[4], A2[2], A3[4][2], A4[4][2], A5[2];
#pragma unroll
    for (int mt = 0; mt < 4; ++mt) { wf.u = wfrags[(0 + mt) * 64 + lane]; A1[mt] = wf.v; }
#pragma unroll
    for (int kt = 0; kt < 2; ++kt) { wf.u = wfrags[(4 + kt) * 64 + lane]; A2[kt] = wf.v; }
#pragma unroll
    for (int mt = 0; mt < 4; ++mt)
#pragma unroll
        for (int kt = 0; kt < 2; ++kt) {
            wf.u = wfrags[(6 + 2 * mt + kt) * 64 + lane];  A3[mt][kt] = wf.v;
            wf.u = wfrags[(14 + 2 * mt + kt) * 64 + lane]; A4[mt][kt] = wf.v;
        }
#pragma unroll
    for (int kt = 0; kt < 2; ++kt) { wf.u = wfrags[(22 + kt) * 64 + lane]; A5[kt] = wf.v; }

    for (int it = 0; it < 8; ++it) {
        int g = (wgid * 8 + it) << 4;        // point base of this 16-group
        int pt = g + col;
        size_t pt3 = (size_t)pt * 3;

        // ---- B-frag of feats: pair index k/2 = q*4+w
        union { bf16x8 v; uint32_t d[4]; } Bf;
#pragma unroll
        for (int w = 0; w < 4; ++w)
            Bf.d[w] = feats[(size_t)(q * 4 + w) * NPTS + g + col];

        // ---- L1: feats(32) -> h1(64), bias, relu
        f32x4 T[4];
#pragma unroll
        for (int mt = 0; mt < 4; ++mt) {
            const float4 bb = *(const float4*)&db1[mt * 16 + q * 4];
            f32x4 c; c[0] = bb.x; c[1] = bb.y; c[2] = bb.z; c[3] = bb.w;
            T[mt] = MFMA_BF16(A1[mt], Bf.v, c, 0, 0, 0);
        }
        uint32_t p01[4], p23[4];
#pragma unroll
        for (int mt = 0; mt < 4; ++mt) {
            p01[mt] = pack2(fmaxf(T[mt][0], 0.f), fmaxf(T[mt][1], 0.f));
            p23[mt] = pack2(fmaxf(T[mt][2], 0.f), fmaxf(T[mt][3], 0.f));
        }
        bf16x8 Bh0 = trans_frag(p01[0], p23[0], p01[1], p23[1], lane);
        bf16x8 Bh1 = trans_frag(p01[2], p23[2], p01[3], p23[3], lane);

        // ---- L2: h1(64) -> log_sigma(16), bias, linear
        f32x4 Dls;
        {
            const float4 bb = *(const float4*)&db2[q * 4];
            f32x4 c; c[0] = bb.x; c[1] = bb.y; c[2] = bb.z; c[3] = bb.w;
            Dls = MFMA_BF16(A2[0], Bh0, c, 0, 0, 0);
            Dls = MFMA_BF16(A2[1], Bh1, Dls, 0, 0, 0);
        }
        uint32_t lp01 = pack2(Dls[0], Dls[1]);
        uint32_t lp23 = pack2(Dls[2], Dls[3]);

        // ---- av B-frags: rows 0..15 = ls, 16..42 = dir PE, 43 = 1, rest 0
        float rx = rdir[pt3 + 0], ry = rdir[pt3 + 1], rz = rdir[pt3 + 2];

        union { bf16x8 v; uint32_t d[4]; } Ba0, Ba1;
        Ba0.v = trans_frag(lp01, lp23, lp01, lp23, lane);  // valid for q<2
        {
            int base = q << 3;
#pragma unroll
            for (int j = 0; j < 4; ++j) {
                uint32_t pk = pack2(pe_val(base + 2 * j, rx, ry, rz),
                                    pe_val(base + 2 * j + 1, rx, ry, rz));
                if (q >= 2) Ba0.d[j] = pk;                  // rows 16..31
            }
        }
        {
            int base = 32 + (q << 3);
#pragma unroll
            for (int j = 0; j < 4; ++j)
                Ba1.d[j] = pack2(pe_val(base + 2 * j, rx, ry, rz),
                                 pe_val(base + 2 * j + 1, rx, ry, rz));
        }

        // ---- L3: av(43+1) -> c1(64), bias folded via row 43, relu
        f32x4 C1[4];
#pragma unroll
        for (int mt = 0; mt < 4; ++mt) {
            f32x4 c = {0.f, 0.f, 0.f, 0.f};
            c = MFMA_BF16(A3[mt][0], Ba0.v, c, 0, 0, 0);
            C1[mt] = MFMA_BF16(A3[mt][1], Ba1.v, c, 0, 0, 0);
        }
#pragma unroll
        for (int mt = 0; mt < 4; ++mt) {
            p01[mt] = pack2(fmaxf(C1[mt][0], 0.f), fmaxf(C1[mt][1], 0.f));
            p23[mt] = pack2(fmaxf(C1[mt][2], 0.f), fmaxf(C1[mt][3], 0.f));
        }
        bf16x8 Bc0 = trans_frag(p01[0], p23[0], p01[1], p23[1], lane);
        bf16x8 Bc1 = trans_frag(p01[2], p23[2], p01[3], p23[3], lane);

        // ---- L4: c1(64) -> c2(64), bias, relu
        f32x4 C2[4];
#pragma unroll
        for (int mt = 0; mt < 4; ++mt) {
            const float4 bb = *(const float4*)&cb2[mt * 16 + q * 4];
            f32x4 c; c[0] = bb.x; c[1] = bb.y; c[2] = bb.z; c[3] = bb.w;
            c = MFMA_BF16(A4[mt][0], Bc0, c, 0, 0, 0);
            C2[mt] = MFMA_BF16(A4[mt][1], Bc1, c, 0, 0, 0);
        }
#pragma unroll
        for (int mt = 0; mt < 4; ++mt) {
            p01[mt] = pack2(fmaxf(C2[mt][0], 0.f), fmaxf(C2[mt][1], 0.f));
            p23[mt] = pack2(fmaxf(C2[mt][2], 0.f), fmaxf(C2[mt][3], 0.f));
        }
        bf16x8 Bd0 = trans_frag(p01[0], p23[0], p01[1], p23[1], lane);
        bf16x8 Bd1 = trans_frag(p01[2], p23[2], p01[3], p23[3], lane);

        // ---- L5: c2(64) -> color(3), bias, sigmoid
        f32x4 c5 = {0.f, 0.f, 0.f, 0.f};
        if (q == 0) { c5[0] = cb3[0]; c5[1] = cb3[1]; c5[2] = cb3[2]; }
        f32x4 Dc = MFMA_BF16(A5[0], Bd0, c5, 0, 0, 0);
        Dc = MFMA_BF16(A5[1], Bd1, Dc, 0, 0, 0);

        // ---- outputs
        if (q == 0) {
            float xfx = x[pt3 + 0] + 0.5f;
            float xfy = x[pt3 + 1] + 0.5f;
            float xfz = x[pt3 + 2] + 0.5f;
            bool m = (xfx > 0.f) && (xfx < 1.f) && (xfy > 0.f) && (xfy < 1.f) &&
                     (xfz > 0.f) && (xfz < 1.f);
            out[pt3 + 0] = m ? 1.f / (1.f + __expf(-Dc[0])) : 0.f;
            out[pt3 + 1] = m ? 1.f / (1.f + __expf(-Dc[1])) : 0.f;
            out[pt3 + 2] = m ? 1.f / (1.f + __expf(-Dc[2])) : 0.f;
            out[(size_t)3 * NPTS + pt] = m ? __expf(Dls[0]) : 0.f;
        }
    }
}

extern "C" void kernel_launch(void* const* d_in, const int* in_sizes, int n_in,
                              void* d_out, int out_size, void* d_ws, size_t ws_size,
                              hipStream_t stream) {
    const float* x      = (const float*)d_in[0];
    const float* rdir   = (const float*)d_in[1];
    const float* tables = (const float*)d_in[2];
    const float* dW1 = (const float*)d_in[3];
    const float* db1 = (const float*)d_in[4];
    const float* dW2 = (const float*)d_in[5];
    const float* db2 = (const float*)d_in[6];
    const float* cW1 = (const float*)d_in[7];
    const float* cb1 = (const float*)d_in[8];
    const float* cW2 = (const float*)d_in[9];
    const float* cb2 = (const float*)d_in[10];
    const float* cW3 = (const float*)d_in[11];
    const float* cb3 = (const float*)d_in[12];
    float* out = (float*)d_out;

    uint4*    wfrags = (uint4*)d_ws;                        // 24 KB
    uint32_t* feats  = (uint32_t*)((char*)d_ws + 32768);    // 16*NPTS*4 B

    k_encode<<<ENC_BLOCKS + PREP_BLOCKS, 256, 0, stream>>>(
        x, tables, feats, dW1, dW2, cW1, cb1, cW2, cW3, wfrags);
    k_mlp<<<MLP_BLOCKS, 256, 0, stream>>>(feats, wfrags, x, rdir,
                                          db1, db2, cb2, cb3, out);
}

// Round 7
// 248.880 us; speedup vs baseline: 1.6678x; 1.0324x over previous
//
#include <hip/hip_runtime.h>
#include <hip/hip_bf16.h>
#include <cstdint>

#define NPTS (2048 * 192)          // 393216 points
#define TBL  (1u << 19)            // hash table size per level
#define TMASK (TBL - 1u)
#define PBLOCKS (NPTS / 256)       // 1536 blocks per level
#define ENC_BLOCKS (PBLOCKS * 16)  // 24576
#define PREP_BLOCKS 6              // 24 frags * 64 lanes / 256
#define MLP_BLOCKS 1536            // 1536 blocks * 4 waves * 4 groups * 16 pts
#define P2 2654435761u
#define P3 805459861u

// geomspace(16, 2048, 16).astype(int)
__constant__ float LVLS[16] = {16.f, 22.f, 30.f, 42.f, 58.f, 80.f, 111.f, 153.f,
                               212.f, 294.f, 406.f, 561.f, 776.f, 1072.f, 1482.f, 2048.f};

__device__ __forceinline__ uint32_t f2bf(float f) {
    uint32_t u = __float_as_uint(f);
    return (u + 0x7FFFu + ((u >> 16) & 1u)) >> 16;   // RNE bf16 (weights/feats)
}
__device__ __forceinline__ uint32_t pack2(float a, float b) {
    return f2bf(a) | (f2bf(b) << 16);
}
// 1-instruction truncating bf16 pack: [a_hi16 | b_hi16 << 16] via v_perm_b32.
// RTZ costs <=1 extra ulp vs RNE; activation path has 5x absmax headroom.
__device__ __forceinline__ uint32_t pack2t(float a, float b) {
    return __builtin_amdgcn_perm(__float_as_uint(b), __float_as_uint(a),
                                 0x07060302u);
}

#if __has_builtin(__builtin_amdgcn_sinf)
#define SIN_REV(x) __builtin_amdgcn_sinf(x)   // sin(2*pi*x)
#else
#define SIN_REV(x) __sinf(6.28318530717958647f * (x))
#endif

typedef __attribute__((ext_vector_type(8))) short bf16x8;   // MFMA A/B frag
typedef __attribute__((ext_vector_type(4))) float f32x4;    // MFMA C/D frag

#define MFMA_BF16 __builtin_amdgcn_mfma_f32_16x16x32_bf16

// ---------------------------------------------------------------------------
// Kernel 1: hash-grid encode + (tail blocks) weight-fragment prepack.
// UNCHANGED from round 6 — at ~90% of the TCC request-rate floor
// (~32M L2 requests / 128 channels / 2.4GHz ~= 105us), FETCH 131MB.
// XCD-affine level mapping keeps one 4MB table per XCD L2 at a time.
// ---------------------------------------------------------------------------
__global__ __launch_bounds__(256) void k_encode(const float* __restrict__ x,
                                                const float* __restrict__ tables,
                                                uint32_t* __restrict__ feats,
                                                const float* __restrict__ dW1,
                                                const float* __restrict__ dW2,
                                                const float* __restrict__ cW1,
                                                const float* __restrict__ cb1,
                                                const float* __restrict__ cW2,
                                                const float* __restrict__ cW3,
                                                uint4* __restrict__ wfrags)
{
    if (blockIdx.x >= ENC_BLOCKS) {
        // ---- weight prepack (6 tail blocks; consumed by k_mlp) ----
        int t = (blockIdx.x - ENC_BLOCKS) * 256 + threadIdx.x;
        if (t >= 24 * 64) return;
        int frag = t >> 6, lane = t & 63;
        const float* W; const float* bfold = nullptr;
        int OUT, Kact, Mact, k0, m0;
        if (frag < 4)       { W = dW1; OUT = 64; Kact = 32; Mact = 64; k0 = 0;               m0 = frag * 16; }
        else if (frag < 6)  { W = dW2; OUT = 16; Kact = 64; Mact = 16; k0 = (frag - 4) * 32; m0 = 0; }
        else if (frag < 14) { int i = frag - 6;  W = cW1; OUT = 64; Kact = 43; Mact = 64;
                              k0 = (i & 1) * 32; m0 = (i >> 1) * 16; bfold = cb1; }
        else if (frag < 22) { int i = frag - 14; W = cW2; OUT = 64; Kact = 64; Mact = 64;
                              k0 = (i & 1) * 32; m0 = (i >> 1) * 16; }
        else                { W = cW3; OUT = 3;  Kact = 64; Mact = 3;  k0 = (frag - 22) * 32; m0 = 0; }
        int m  = m0 + (lane & 15);
        int kq = k0 + ((lane >> 4) << 3);
        uint32_t d[4];
#pragma unroll
        for (int j = 0; j < 4; ++j) {
            float a0 = 0.f, a1 = 0.f;
            int ka = kq + 2 * j, kb = ka + 1;
            if (m < Mact) {
                a0 = (ka < Kact) ? W[(size_t)ka * OUT + m]
                                 : ((bfold && ka == Kact) ? bfold[m] : 0.f);
                a1 = (kb < Kact) ? W[(size_t)kb * OUT + m]
                                 : ((bfold && kb == Kact) ? bfold[m] : 0.f);
            }
            d[j] = f2bf(a0) | (f2bf(a1) << 16);
        }
        wfrags[t] = make_uint4(d[0], d[1], d[2], d[3]);
        return;
    }

    // ---- XCD-affine decode of (level, point-block) ----
    int xs   = blockIdx.x & 7;          // XCD slot
    int i    = blockIdx.x >> 3;         // 0..3071
    int half = i / PBLOCKS;             // 0: levels 0-7, 1: levels 8-15
    int pb   = i - half * PBLOCKS;      // point-block 0..1535
    int lvl  = xs + (half << 3);
    int p    = pb * 256 + threadIdx.x;

    size_t p3 = (size_t)p * 3;
    float x0 = x[p3 + 0] + 0.5f;
    float x1 = x[p3 + 1] + 0.5f;
    float x2 = x[p3 + 2] + 0.5f;
    size_t oidx = (size_t)lvl * NPTS + p;

    bool m = (x0 > 0.f) && (x0 < 1.f) && (x1 > 0.f) && (x1 < 1.f) &&
             (x2 > 0.f) && (x2 < 1.f);
    if (!m) { feats[oidx] = 0u; return; }   // masked: features never used

    float s  = LVLS[lvl];
    float px = x0 * s, py = x1 * s, pz = x2 * s;
    float flx = floorf(px), fly = floorf(py), flz = floorf(pz);
    float frx = px - flx,   fry = py - fly,   frz = pz - flz;
    int ix = (int)flx, iy = (int)fly, iz = (int)flz;
    uint32_t ux = (uint32_t)ix, uy = (uint32_t)iy, uz = (uint32_t)iz;

    uint32_t base[4];
    base[0] = (uy * P2) ^ (uz * P3);
    base[1] = ((uy + 1u) * P2) ^ (uz * P3);
    base[2] = (uy * P2) ^ ((uz + 1u) * P3);
    base[3] = ((uy + 1u) * P2) ^ ((uz + 1u) * P3);

    const float2* tb = (const float2*)tables + (size_t)lvl * TBL;

    float2 v[8];
    if ((ix & 1) == 0) {
        // even ix: corners (ix, ix+1) live at (h, h^1) -> one aligned float4
        const float4* tb4 = (const float4*)tb;
#pragma unroll
        for (int cc = 0; cc < 4; ++cc) {
            uint32_t h0 = (base[cc] ^ ux) & TMASK;
            float4 qv = tb4[h0 >> 1];
            bool hi = (h0 & 1u) != 0u;
            float2 e0 = hi ? make_float2(qv.z, qv.w) : make_float2(qv.x, qv.y);
            float2 e1 = hi ? make_float2(qv.x, qv.y) : make_float2(qv.z, qv.w);
            v[(cc << 1)]     = e0;
            v[(cc << 1) | 1] = e1;
        }
    } else {
        uint32_t h[8];
#pragma unroll
        for (int c = 0; c < 8; ++c)
            h[c] = (base[c >> 1] ^ (ux + (uint32_t)(c & 1))) & TMASK;
#pragma unroll
        for (int c = 0; c < 8; ++c) v[c] = tb[h[c]];
    }

    float f0 = 0.f, f1 = 0.f;
#pragma unroll
    for (int c = 0; c < 8; ++c) {
        float w = ((c & 1)        ? frx : 1.f - frx)
                * (((c >> 1) & 1) ? fry : 1.f - fry)
                * (((c >> 2) & 1) ? frz : 1.f - frz);
        f0 += w * v[c].x;
        f1 += w * v[c].y;
    }
    feats[oidx] = pack2(f0, f1);
}

// ---------------------------------------------------------------------------
// MFMA layout helpers (verified gfx950):
//   A-frag: A[m][k], m = lane&15, k = (lane>>4)*8 + j
//   B-frag: B[k][n], n = lane&15, k = (lane>>4)*8 + j
//   C/D:    D[row][col], col = lane&15, row = (lane>>4)*4 + reg
// ---------------------------------------------------------------------------
__device__ __forceinline__ bf16x8 trans_frag(uint32_t p01a, uint32_t p23a,
                                             uint32_t p01b, uint32_t p23b, int lane)
{
    int q = lane >> 4, col = lane & 15;
    int srcA = (((q & 1) << 1) << 4) | col;   // src quad 2*(q&1)
    int srcB = srcA + 16;                     // src quad 2*(q&1)+1
    uint32_t a0 = (uint32_t)__shfl((int)p01a, srcA, 64);
    uint32_t b0 = (uint32_t)__shfl((int)p01b, srcA, 64);
    uint32_t a1 = (uint32_t)__shfl((int)p23a, srcA, 64);
    uint32_t b1 = (uint32_t)__shfl((int)p23b, srcA, 64);
    uint32_t a2 = (uint32_t)__shfl((int)p01a, srcB, 64);
    uint32_t b2 = (uint32_t)__shfl((int)p01b, srcB, 64);
    uint32_t a3 = (uint32_t)__shfl((int)p23a, srcB, 64);
    uint32_t b3 = (uint32_t)__shfl((int)p23b, srcB, 64);
    bool hi = q >= 2;
    union { bf16x8 v; uint32_t d[4]; } u;
    u.d[0] = hi ? b0 : a0;
    u.d[1] = hi ? b1 : a1;
    u.d[2] = hi ? b2 : a2;
    u.d[3] = hi ? b3 : a3;
    return u.v;
}

// av-vector row value for rows 16..63. ONE transcendental per row:
// cos(x) = sin(x + 0.25 rev), so select the angle offset instead of
// computing both sin and cos (round-6 post-mortem: pe_val was 2x the
// needed transcendental work).
__device__ __forceinline__ float pe_val(int r, float rx, float ry, float rz)
{
    int t = r - 19;
    int d = t >> 3;
    int s = t & 7;
    float comp = (d == 0) ? rx : ((d == 1) ? ry : rz);
    float a = ldexpf(comp, s & 3) + ((s >= 4) ? 0.25f : 0.0f);
    float v = SIN_REV(a);
    if (r == 16) v = rx;
    if (r == 17) v = ry;
    if (r == 18) v = rz;
    if (r == 43) v = 1.0f;
    if (r > 43)  v = 0.0f;
    return v;
}

// ---------------------------------------------------------------------------
// Kernel 2: MLP stack on matrix cores. Wave = 16 points per group (N dim),
// 4 groups/wave. Weight fragments loaded coalesced from prepacked d_ws.
// Activation packs are single v_perm_b32 (truncating bf16).
// ---------------------------------------------------------------------------
__global__ __launch_bounds__(256) void k_mlp(const uint32_t* __restrict__ feats,
                                             const uint4* __restrict__ wfrags,
                                             const float* __restrict__ x,
                                             const float* __restrict__ rdir,
                                             const float* __restrict__ db1,
                                             const float* __restrict__ db2,
                                             const float* __restrict__ cb2,
                                             const float* __restrict__ cb3,
                                             float* __restrict__ out)
{
    int lane = threadIdx.x & 63;
    int q = lane >> 4, col = lane & 15;
    int wgid = blockIdx.x * 4 + (threadIdx.x >> 6);

    // ---- persistent weight fragments: 24 coalesced dwordx4 loads ----
    union { bf16x8 v; uint4 u; } wf;
    bf16x8 A1[4], A2[2], A3[4][2], A4[4][2], A5[2];
#pragma unroll
    for (int mt = 0; mt < 4; ++mt) { wf.u = wfrags[(0 + mt) * 64 + lane]; A1[mt] = wf.v; }
#pragma unroll
    for (int kt = 0; kt < 2; ++kt) { wf.u = wfrags[(4 + kt) * 64 + lane]; A2[kt] = wf.v; }
#pragma unroll
    for (int mt = 0; mt < 4; ++mt)
#pragma unroll
        for (int kt = 0; kt < 2; ++kt) {
            wf.u = wfrags[(6 + 2 * mt + kt) * 64 + lane];  A3[mt][kt] = wf.v;
            wf.u = wfrags[(14 + 2 * mt + kt) * 64 + lane]; A4[mt][kt] = wf.v;
        }
#pragma unroll
    for (int kt = 0; kt < 2; ++kt) { wf.u = wfrags[(22 + kt) * 64 + lane]; A5[kt] = wf.v; }

    for (int it = 0; it < 4; ++it) {
        int g = (wgid * 4 + it) << 4;        // point base of this 16-group
        int pt = g + col;
        size_t pt3 = (size_t)pt * 3;

        // ---- B-frag of feats: pair index k/2 = q*4+w
        union { bf16x8 v; uint32_t d[4]; } Bf;
#pragma unroll
        for (int w = 0; w < 4; ++w)
            Bf.d[w] = feats[(size_t)(q * 4 + w) * NPTS + g + col];

        // ---- L1: feats(32) -> h1(64), bias, relu
        f32x4 T[4];
#pragma unroll
        for (int mt = 0; mt < 4; ++mt) {
            const float4 bb = *(const float4*)&db1[mt * 16 + q * 4];
            f32x4 c; c[0] = bb.x; c[1] = bb.y; c[2] = bb.z; c[3] = bb.w;
            T[mt] = MFMA_BF16(A1[mt], Bf.v, c, 0, 0, 0);
        }
        uint32_t p01[4], p23[4];
#pragma unroll
        for (int mt = 0; mt < 4; ++mt) {
            p01[mt] = pack2t(fmaxf(T[mt][0], 0.f), fmaxf(T[mt][1], 0.f));
            p23[mt] = pack2t(fmaxf(T[mt][2], 0.f), fmaxf(T[mt][3], 0.f));
        }
        bf16x8 Bh0 = trans_frag(p01[0], p23[0], p01[1], p23[1], lane);
        bf16x8 Bh1 = trans_frag(p01[2], p23[2], p01[3], p23[3], lane);

        // ---- L2: h1(64) -> log_sigma(16), bias, linear
        f32x4 Dls;
        {
            const float4 bb = *(const float4*)&db2[q * 4];
            f32x4 c; c[0] = bb.x; c[1] = bb.y; c[2] = bb.z; c[3] = bb.w;
            Dls = MFMA_BF16(A2[0], Bh0, c, 0, 0, 0);
            Dls = MFMA_BF16(A2[1], Bh1, Dls, 0, 0, 0);
        }
        uint32_t lp01 = pack2t(Dls[0], Dls[1]);
        uint32_t lp23 = pack2t(Dls[2], Dls[3]);

        // ---- av B-frags: rows 0..15 = ls, 16..42 = dir PE, 43 = 1, rest 0
        float rx = rdir[pt3 + 0], ry = rdir[pt3 + 1], rz = rdir[pt3 + 2];

        union { bf16x8 v; uint32_t d[4]; } Ba0, Ba1;
        Ba0.v = trans_frag(lp01, lp23, lp01, lp23, lane);  // valid for q<2
        {
            int base = q << 3;
#pragma unroll
            for (int j = 0; j < 4; ++j) {
                uint32_t pk = pack2t(pe_val(base + 2 * j, rx, ry, rz),
                                     pe_val(base + 2 * j + 1, rx, ry, rz));
                if (q >= 2) Ba0.d[j] = pk;                  // rows 16..31
            }
        }
        {
            int base = 32 + (q << 3);
#pragma unroll
            for (int j = 0; j < 4; ++j)
                Ba1.d[j] = pack2t(pe_val(base + 2 * j, rx, ry, rz),
                                  pe_val(base + 2 * j + 1, rx, ry, rz));
        }

        // ---- L3: av(43+1) -> c1(64), bias folded via row 43, relu
        f32x4 C1[4];
#pragma unroll
        for (int mt = 0; mt < 4; ++mt) {
            f32x4 c = {0.f, 0.f, 0.f, 0.f};
            c = MFMA_BF16(A3[mt][0], Ba0.v, c, 0, 0, 0);
            C1[mt] = MFMA_BF16(A3[mt][1], Ba1.v, c, 0, 0, 0);
        }
#pragma unroll
        for (int mt = 0; mt < 4; ++mt) {
            p01[mt] = pack2t(fmaxf(C1[mt][0], 0.f), fmaxf(C1[mt][1], 0.f));
            p23[mt] = pack2t(fmaxf(C1[mt][2], 0.f), fmaxf(C1[mt][3], 0.f));
        }
        bf16x8 Bc0 = trans_frag(p01[0], p23[0], p01[1], p23[1], lane);
        bf16x8 Bc1 = trans_frag(p01[2], p23[2], p01[3], p23[3], lane);

        // ---- L4: c1(64) -> c2(64), bias, relu
        f32x4 C2[4];
#pragma unroll
        for (int mt = 0; mt < 4; ++mt) {
            const float4 bb = *(const float4*)&cb2[mt * 16 + q * 4];
            f32x4 c; c[0] = bb.x; c[1] = bb.y; c[2] = bb.z; c[3] = bb.w;
            c = MFMA_BF16(A4[mt][0], Bc0, c, 0, 0, 0);
            C2[mt] = MFMA_BF16(A4[mt][1], Bc1, c, 0, 0, 0);
        }
#pragma unroll
        for (int mt = 0; mt < 4; ++mt) {
            p01[mt] = pack2t(fmaxf(C2[mt][0], 0.f), fmaxf(C2[mt][1], 0.f));
            p23[mt] = pack2t(fmaxf(C2[mt][2], 0.f), fmaxf(C2[mt][3], 0.f));
        }
        bf16x8 Bd0 = trans_frag(p01[0], p23[0], p01[1], p23[1], lane);
        bf16x8 Bd1 = trans_frag(p01[2], p23[2], p01[3], p23[3], lane);

        // ---- L5: c2(64) -> color(3), bias, sigmoid
        f32x4 c5 = {0.f, 0.f, 0.f, 0.f};
        if (q == 0) { c5[0] = cb3[0]; c5[1] = cb3[1]; c5[2] = cb3[2]; }
        f32x4 Dc = MFMA_BF16(A5[0], Bd0, c5, 0, 0, 0);
        Dc = MFMA_BF16(A5[1], Bd1, Dc, 0, 0, 0);

        // ---- outputs
        if (q == 0) {
            float xfx = x[pt3 + 0] + 0.5f;
            float xfy = x[pt3 + 1] + 0.5f;
            float xfz = x[pt3 + 2] + 0.5f;
            bool m = (xfx > 0.f) && (xfx < 1.f) && (xfy > 0.f) && (xfy < 1.f) &&
                     (xfz > 0.f) && (xfz < 1.f);
            out[pt3 + 0] = m ? 1.f / (1.f + __expf(-Dc[0])) : 0.f;
            out[pt3 + 1] = m ? 1.f / (1.f + __expf(-Dc[1])) : 0.f;
            out[pt3 + 2] = m ? 1.f / (1.f + __expf(-Dc[2])) : 0.f;
            out[(size_t)3 * NPTS + pt] = m ? __expf(Dls[0]) : 0.f;
        }
    }
}

extern "C" void kernel_launch(void* const* d_in, const int* in_sizes, int n_in,
                              void* d_out, int out_size, void* d_ws, size_t ws_size,
                              hipStream_t stream) {
    const float* x      = (const float*)d_in[0];
    const float* rdir   = (const float*)d_in[1];
    const float* tables = (const float*)d_in[2];
    const float* dW1 = (const float*)d_in[3];
    const float* db1 = (const float*)d_in[4];
    const float* dW2 = (const float*)d_in[5];
    const float* db2 = (const float*)d_in[6];
    const float* cW1 = (const float*)d_in[7];
    const float* cb1 = (const float*)d_in[8];
    const float* cW2 = (const float*)d_in[9];
    const float* cb2 = (const float*)d_in[10];
    const float* cW3 = (const float*)d_in[11];
    const float* cb3 = (const float*)d_in[12];
    float* out = (float*)d_out;

    uint4*    wfrags = (uint4*)d_ws;                        // 24 KB
    uint32_t* feats  = (uint32_t*)((char*)d_ws + 32768);    // 16*NPTS*4 B

    k_encode<<<ENC_BLOCKS + PREP_BLOCKS, 256, 0, stream>>>(
        x, tables, feats, dW1, dW2, cW1, cb1, cW2, cW3, wfrags);
    k_mlp<<<MLP_BLOCKS, 256, 0, stream>>>(feats, wfrags, x, rdir,
                                          db1, db2, cb2, cb3, out);
}